// Round 20
// baseline (985.515 us; speedup 1.0000x reference)
//
#include <hip/hip_runtime.h>
#include <cstdint>
#include <cstddef>

#define DIN 128       // feature width of all layer inputs (and Q/K/V width = H*DH)
#define ROW_BYTES 1024 // per-node row: Q bf16 [0,256) (head h at h*64)
                       //   K bf16 chunk-transposed [256,512): chunk j at 256+j*64 = [h0|h1|h2|h3]x16B
                       //   V bf16 chunk-transposed [512,768)
                       //   S bf16 linear [768,1024)

typedef __attribute__((ext_vector_type(8))) short short8v;
typedef __attribute__((ext_vector_type(4))) float float4v;

// ---------------- CSR build ----------------
__global__ void k_count(const int* __restrict__ dst, int* __restrict__ deg, int E){
  int i = blockIdx.x*blockDim.x + threadIdx.x;
  if(i<E) atomicAdd(&deg[dst[i]], 1);
}

__global__ void k_scan1(const int* __restrict__ deg, int* __restrict__ offs,
                        int* __restrict__ part, int n){
  __shared__ int sm[256];
  int t = threadIdx.x; int g = blockIdx.x*256 + t;
  int v = (g<n)? deg[g] : 0;
  sm[t] = v;
  for(int o=1;o<256;o<<=1){
    __syncthreads();
    int x = (t>=o)? sm[t-o] : 0;
    __syncthreads();
    sm[t] += x;
  }
  __syncthreads();
  if(g<n) offs[g+1] = sm[t];
  if(t==255) part[blockIdx.x] = sm[255];
}

__global__ void k_scan2(int* __restrict__ part, int nb){
  __shared__ int sm[256];
  int t=threadIdx.x;
  int v = (t<nb)? part[t] : 0;
  sm[t]=v;
  for(int o=1;o<256;o<<=1){ __syncthreads(); int x=(t>=o)?sm[t-o]:0; __syncthreads(); sm[t]+=x; }
  __syncthreads();
  if(t<nb) part[t] = sm[t]-v;  // exclusive prefix of block totals
}

__global__ void k_scan3(int* __restrict__ offs, const int* __restrict__ part, int n){
  int t=threadIdx.x; int g=blockIdx.x*256+t;
  if(g<n) offs[g+1] += part[blockIdx.x];
  if(g==0) offs[0]=0;
}

__global__ void k_scatter(const int* __restrict__ src, const int* __restrict__ dst,
                          const int* __restrict__ offs, int* __restrict__ cur,
                          int* __restrict__ srcs, int E){
  int i=blockIdx.x*blockDim.x+threadIdx.x;
  if(i<E){
    int d = dst[i];
    int p = atomicAdd(&cur[d],1);
    srcs[offs[d]+p] = src[i];
  }
}

// bf16 helpers (bf16 = top 16 bits of fp32; RNE pack)
__device__ inline unsigned f2bf(float x){
  unsigned u = __float_as_uint(x);
  return (u + 0x7FFFu + ((u>>16)&1u)) >> 16;
}
__device__ inline unsigned pack2(float a, float b){ return f2bf(a) | (f2bf(b)<<16); }
__device__ inline float bflo(unsigned w){ return __uint_as_float(w<<16); }
__device__ inline float bfhi(unsigned w){ return __uint_as_float(w & 0xFFFF0000u); }

// ---------------- weight prep: fp32 [din][dout] -> bf16 transposed [dout][din] ----------------
__global__ void k_wt(
  const float* __restrict__ W0, const float* __restrict__ W1, const float* __restrict__ W2,
  const float* __restrict__ W3, const float* __restrict__ W4, const float* __restrict__ W5,
  const float* __restrict__ W6, const float* __restrict__ W7, const float* __restrict__ W8,
  const float* __restrict__ W9, const float* __restrict__ W10, const float* __restrict__ W11,
  unsigned short* __restrict__ wt)
{
  int i = blockIdx.y;
  int e = blockIdx.x*256 + threadIdx.x;
  int dout = (i==11)? 32 : 128;
  if(e >= dout*128) return;
  const float* W;
  switch(i){
    case 0: W=W0; break; case 1: W=W1; break; case 2: W=W2; break; case 3: W=W3; break;
    case 4: W=W4; break; case 5: W=W5; break; case 6: W=W6; break; case 7: W=W7; break;
    case 8: W=W8; break; case 9: W=W9; break; case 10: W=W10; break; default: W=W11; break;
  }
  int c = e % dout, k = e / dout;
  wt[i*16384 + c*128 + k] = (unsigned short)f2bf(W[(size_t)k*dout + c]);
}

// ---------------- fused QKVS GEMM (bf16 MFMA, fp32 accum, 4 mats per block) ----------------
// grid: 1D row tiles. Block stages X ONCE. Passes linearized: p -> (mat=p>>1,
// half=p&1); next pass's 16KB W slice register-prefetched during this pass's
// MFMA (straight-line, static regs). Epilogue: Q,S bf16; K,V chunk-transposed.
__global__ __launch_bounds__(256,4) void k_gemm(
  const void* __restrict__ Xv, int xbf, int nrows,
  const unsigned short* __restrict__ Wt,
  const float* __restrict__ bq, const float* __restrict__ bk,
  const float* __restrict__ bv, const float* __restrict__ bs,
  int ws_cols, char* __restrict__ out)
{
  __shared__ unsigned short Xs[64][136];
  __shared__ unsigned short Wsh[64][136];
  int t = threadIdx.x;
  int row0 = blockIdx.x*64;
  int c = t>>2, kb = (t&3)*32;
  // ---- stage X (once) ----
  {
    int gr = row0 + c;
    if(gr < nrows){
      if(xbf){
        const unsigned short* xp = (const unsigned short*)Xv + (size_t)gr*DIN + kb;
        #pragma unroll
        for(int j=0;j<4;j++)
          *(uint4*)&Xs[c][kb + j*8] = *(const uint4*)(xp + j*8);
      } else {
        const float* xp = (const float*)Xv + (size_t)gr*DIN + kb;
        #pragma unroll
        for(int j=0;j<4;j++){
          float4 fa = *(const float4*)(xp + j*8);
          float4 fb = *(const float4*)(xp + j*8 + 4);
          uint4 pk = make_uint4(pack2(fa.x,fa.y), pack2(fa.z,fa.w),
                                pack2(fb.x,fb.y), pack2(fb.z,fb.w));
          *(uint4*)&Xs[c][kb + j*8] = pk;
        }
      }
    } else {
      uint4 z = make_uint4(0,0,0,0);
      #pragma unroll
      for(int j=0;j<4;j++) *(uint4*)&Xs[c][kb + j*8] = z;
    }
  }
  int wv = t>>6, l = t&63;
  int lr = l & 15, lk = (l>>4)*8;
  int P = (ws_cols > 64) ? 8 : 7;
  // prefetch pass 0 W slice (mat 0, half 0)
  uint4 w0, w1, w2, w3;
  {
    const unsigned short* wp = Wt + (size_t)c*128 + kb;
    w0 = *(const uint4*)(wp);
    w1 = *(const uint4*)(wp + 8);
    w2 = *(const uint4*)(wp + 16);
    w3 = *(const uint4*)(wp + 24);
  }
  for(int p=0; p<P; p++){
    int mat = p>>1, half = p&1;
    int wcols = (mat==3)? ws_cols : 128;
    int col0 = half*64;
    __syncthreads();    // prev pass's Wsh consumers done (p=0: Xs staged)
    *(uint4*)&Wsh[c][kb]      = w0;
    *(uint4*)&Wsh[c][kb + 8]  = w1;
    *(uint4*)&Wsh[c][kb + 16] = w2;
    *(uint4*)&Wsh[c][kb + 24] = w3;
    if(p+1 < P){
      int m2 = (p+1)>>1, h2 = (p+1)&1;
      const unsigned short* wp = Wt + m2*16384 + (size_t)(h2*64 + c)*128 + kb;
      w0 = *(const uint4*)(wp);
      w1 = *(const uint4*)(wp + 8);
      w2 = *(const uint4*)(wp + 16);
      w3 = *(const uint4*)(wp + 24);
    }
    __syncthreads();    // Wsh ready
    float4v acc[4];
    #pragma unroll
    for(int mt=0;mt<4;mt++) acc[mt] = (float4v){0.f,0.f,0.f,0.f};
    #pragma unroll
    for(int kk=0;kk<4;kk++){
      short8v b = *(const short8v*)&Wsh[wv*16 + lr][kk*32 + lk];
      #pragma unroll
      for(int mt=0;mt<4;mt++){
        short8v a = *(const short8v*)&Xs[mt*16 + lr][kk*32 + lk];
        acc[mt] = __builtin_amdgcn_mfma_f32_16x16x32_bf16(a, b, acc[mt], 0, 0, 0);
      }
    }
    const float* bias = (mat==0)?bq:(mat==1)?bk:(mat==2)?bv:bs;
    int col = col0 + wv*16 + lr;
    bool cok = col < wcols;
    float bcol = cok ? bias[col] : 0.f;
    int rb = row0 + (l>>4)*4;
    #pragma unroll
    for(int mt=0;mt<4;mt++){
      #pragma unroll
      for(int j=0;j<4;j++){
        int r = rb + mt*16 + j;
        if(r < nrows && cok){
          float val = acc[mt][j] + bcol;
          char* rowp = out + ((size_t)r<<10);
          if(mat==0)      *(unsigned short*)(rowp + col*2) = (unsigned short)f2bf(val);
          else if(mat==3) *(unsigned short*)(rowp + 768 + col*2) = (unsigned short)f2bf(val);
          else {
            int h = col>>5, d = col&31;
            int off = ((mat==1)?256:512) + (d>>3)*64 + h*16 + (d&7)*2;
            *(unsigned short*)(rowp + off) = (unsigned short)f2bf(val);
          }
        }
      }
    }
  }
}

// ---------------- per-node attention (online softmax, CSR, chunk-transposed bf16 KV) ----------------
// EXACT round-13 loop (best clean config: 72us, WRITE 12.5MB, VGPR 60), with
// __launch_bounds__(256,8): at <=64 VGPR the HW can host 8 waves/SIMD; the
// (256,4) build left half the wave slots unused (occupancy 34%). No code change
// otherwise — prefetch variant (r19) was null and mildly spilled; removed.
// mode 0: out bf16-packed [N][64] uints = relu(concat agg + skip)
// mode 1: out fp32 [N][32] = mean_h(agg) + skip
__global__ __launch_bounds__(256,8) void k_attn(
  const char* __restrict__ QKVS, const int* __restrict__ offs,
  const int* __restrict__ srcs, void* __restrict__ outv, int mode, int n)
{
  int wv = threadIdx.x>>6, lane = threadIdx.x&63;
  int node = blockIdx.x*4 + wv;
  if(node >= n) return;
  int h = lane & 3;
  int e_l = lane >> 2;
  const float rs = 0.17677669529663687f;  // 1/sqrt(32)
  const char* rowq = QKVS + ((size_t)node<<10) + h*64;
  uint4 qw[4];
  #pragma unroll
  for(int j=0;j<4;j++) qw[j] = *(const uint4*)(rowq + j*16);
  int beg = offs[node], end = offs[node+1];
  float m = 0.f, s = 0.f;
  float4 acc[8];
  #pragma unroll
  for(int j=0;j<8;j++) acc[j] = make_float4(0.f,0.f,0.f,0.f);

  if(beg < end){
    // ---- first batch (peeled: no rescale, acc = p*V) ----
    {
      int idx = beg + e_l;
      bool msk = idx < end;
      int sj = srcs[msk ? idx : beg];
      const char* base = QKVS + ((size_t)sj<<10) + 256 + h*16;
      uint4 vw[4];
      #pragma unroll
      for(int j=0;j<4;j++) vw[j] = *(const uint4*)(base + 256 + j*64);
      #pragma unroll
      for(int j=0;j<4;j++)
        asm volatile("" : "+v"(vw[j].x), "+v"(vw[j].y), "+v"(vw[j].z), "+v"(vw[j].w));
      float dot = 0.f;
      #pragma unroll
      for(int j=0;j<4;j++){
        uint4 kwj = *(const uint4*)(base + j*64);
        uint4 qj = qw[j];
        dot += bflo(qj.x)*bflo(kwj.x) + bfhi(qj.x)*bfhi(kwj.x)
             + bflo(qj.y)*bflo(kwj.y) + bfhi(qj.y)*bfhi(kwj.y)
             + bflo(qj.z)*bflo(kwj.z) + bfhi(qj.z)*bfhi(kwj.z)
             + bflo(qj.w)*bflo(kwj.w) + bfhi(qj.w)*bfhi(kwj.w);
      }
      dot *= rs;
      float logit = msk ? dot : -__builtin_inff();
      float bm = logit;
      bm = fmaxf(bm, __shfl_xor(bm,4));
      bm = fmaxf(bm, __shfl_xor(bm,8));
      bm = fmaxf(bm, __shfl_xor(bm,16));
      bm = fmaxf(bm, __shfl_xor(bm,32));
      float p = __expf(logit - bm);   // invalid lanes -> 0
      float ps = p;
      ps += __shfl_xor(ps,4); ps += __shfl_xor(ps,8); ps += __shfl_xor(ps,16); ps += __shfl_xor(ps,32);
      s = ps; m = bm;
      #pragma unroll
      for(int j=0;j<4;j++){
        uint4 w = vw[j];
        acc[2*j]   = make_float4(p*bflo(w.x), p*bfhi(w.x), p*bflo(w.y), p*bfhi(w.y));
        acc[2*j+1] = make_float4(p*bflo(w.z), p*bfhi(w.z), p*bflo(w.w), p*bfhi(w.w));
      }
    }
    // ---- remaining batches (online softmax with rescale) ----
    for(int b0 = beg+16; b0 < end; b0 += 16){
      int idx = b0 + e_l;
      bool msk = idx < end;
      int sj = srcs[msk ? idx : beg];
      const char* base = QKVS + ((size_t)sj<<10) + 256 + h*16;
      uint4 vw[4];
      #pragma unroll
      for(int j=0;j<4;j++) vw[j] = *(const uint4*)(base + 256 + j*64);
      #pragma unroll
      for(int j=0;j<4;j++)
        asm volatile("" : "+v"(vw[j].x), "+v"(vw[j].y), "+v"(vw[j].z), "+v"(vw[j].w));
      float dot = 0.f;
      #pragma unroll
      for(int j=0;j<4;j++){
        uint4 kwj = *(const uint4*)(base + j*64);
        uint4 qj = qw[j];
        dot += bflo(qj.x)*bflo(kwj.x) + bfhi(qj.x)*bfhi(kwj.x)
             + bflo(qj.y)*bflo(kwj.y) + bfhi(qj.y)*bfhi(kwj.y)
             + bflo(qj.z)*bflo(kwj.z) + bfhi(qj.z)*bfhi(kwj.z)
             + bflo(qj.w)*bflo(kwj.w) + bfhi(qj.w)*bfhi(kwj.w);
      }
      dot *= rs;
      float logit = msk ? dot : -__builtin_inff();
      float bm = logit;
      bm = fmaxf(bm, __shfl_xor(bm,4));
      bm = fmaxf(bm, __shfl_xor(bm,8));
      bm = fmaxf(bm, __shfl_xor(bm,16));
      bm = fmaxf(bm, __shfl_xor(bm,32));
      float mn = fmaxf(m, bm);
      float r = __expf(m - mn);
      float p = __expf(logit - mn);   // invalid lanes -> 0
      float ps = p;
      ps += __shfl_xor(ps,4); ps += __shfl_xor(ps,8); ps += __shfl_xor(ps,16); ps += __shfl_xor(ps,32);
      s = r*s + ps; m = mn;
      #pragma unroll
      for(int j=0;j<4;j++){
        uint4 w = vw[j];
        float4 a0 = acc[2*j], a1 = acc[2*j+1];
        a0.x = fmaf(a0.x, r, p*bflo(w.x)); a0.y = fmaf(a0.y, r, p*bfhi(w.x));
        a0.z = fmaf(a0.z, r, p*bflo(w.y)); a0.w = fmaf(a0.w, r, p*bfhi(w.y));
        a1.x = fmaf(a1.x, r, p*bflo(w.z)); a1.y = fmaf(a1.y, r, p*bfhi(w.z));
        a1.z = fmaf(a1.z, r, p*bflo(w.w)); a1.w = fmaf(a1.w, r, p*bfhi(w.w));
        acc[2*j] = a0; acc[2*j+1] = a1;
      }
    }
  }
  // ---- reduce-scatter over edge lanes: 30 shfl total ----
  int b5 = (lane>>5)&1, b4 = (lane>>4)&1, b3 = (lane>>3)&1, b2 = (lane>>2)&1;
  float4 r4[4];
  #pragma unroll
  for(int j=0;j<4;j++){
    float4 keep = b5 ? acc[j+4] : acc[j];
    float4 send = b5 ? acc[j]   : acc[j+4];
    keep.x += __shfl_xor(send.x,32); keep.y += __shfl_xor(send.y,32);
    keep.z += __shfl_xor(send.z,32); keep.w += __shfl_xor(send.w,32);
    r4[j] = keep;   // ch = 16*b5 + 4*j + c
  }
  float4 r2[2];
  #pragma unroll
  for(int j=0;j<2;j++){
    float4 keep = b4 ? r4[j+2] : r4[j];
    float4 send = b4 ? r4[j]   : r4[j+2];
    keep.x += __shfl_xor(send.x,16); keep.y += __shfl_xor(send.y,16);
    keep.z += __shfl_xor(send.z,16); keep.w += __shfl_xor(send.w,16);
    r2[j] = keep;   // ch = 16*b5 + 8*b4 + 4*j + c
  }
  float4 r1;
  {
    float4 keep = b3 ? r2[1] : r2[0];
    float4 send = b3 ? r2[0] : r2[1];
    keep.x += __shfl_xor(send.x,8); keep.y += __shfl_xor(send.y,8);
    keep.z += __shfl_xor(send.z,8); keep.w += __shfl_xor(send.w,8);
    r1 = keep;      // ch = 16*b5 + 8*b4 + 4*b3 + c
  }
  float fx, fy;
  {
    float kx = b2 ? r1.z : r1.x, ky = b2 ? r1.w : r1.y;
    float sx = b2 ? r1.x : r1.z, sy = b2 ? r1.y : r1.w;
    fx = kx + __shfl_xor(sx,4);
    fy = ky + __shfl_xor(sy,4);   // ch pair = (2*e_l, 2*e_l+1) of head h
  }
  float inv = (s > 0.f) ? (1.f/s) : 0.f;
  if(mode == 0){
    unsigned sw = *(const unsigned*)(QKVS + ((size_t)node<<10) + 768 + h*64 + e_l*4);
    float ox = fmaxf(fmaf(fx, inv, bflo(sw)), 0.f);
    float oy = fmaxf(fmaf(fy, inv, bfhi(sw)), 0.f);
    ((unsigned*)outv)[(size_t)node*64 + h*16 + e_l] = pack2(ox, oy);
  } else {
    float sc = inv*0.25f;
    float ox = fx*sc, oy = fy*sc;
    ox += __shfl_xor(ox,1); oy += __shfl_xor(oy,1);
    ox += __shfl_xor(ox,2); oy += __shfl_xor(oy,2);
    if(h == 0){
      unsigned sw = *(const unsigned*)(QKVS + ((size_t)node<<10) + 768 + e_l*4);
      float* op = (float*)outv + (size_t)node*32 + 2*e_l;
      op[0] = ox + bflo(sw); op[1] = oy + bfhi(sw);
    }
  }
}

extern "C" void kernel_launch(void* const* d_in, const int* in_sizes, int n_in,
                              void* d_out, int out_size, void* d_ws, size_t ws_size,
                              hipStream_t stream) {
  const float* x = (const float*)d_in[0];
  const int* ei = (const int*)d_in[1];
  int n = in_sizes[0]/DIN;
  int E = in_sizes[1]/2;
  const int* esrc = ei;
  const int* edst = ei + E;

  char* w = (char*)d_ws;
  auto alloc = [&](size_t bytes)->char*{
    char* p = w; w += (bytes + 255) & ~(size_t)255; return p;
  };
  int* offs = (int*)alloc((size_t)(n+1)*4);
  int* deg  = (int*)alloc((size_t)n*4);
  int* cur  = (int*)alloc((size_t)n*4);
  int* part = (int*)alloc(256*4);
  int* srcs = (int*)alloc((size_t)E*4);
  char* qkvs = alloc((size_t)n*ROW_BYTES);
  unsigned short* h1 = (unsigned short*)alloc((size_t)n*128*2);
  unsigned short* h2 = (unsigned short*)alloc((size_t)n*128*2);
  unsigned short* wt = (unsigned short*)alloc((size_t)12*16384*2);

  auto f = [&](int i)->const float*{ return (const float*)d_in[i]; };

  // weight prep (bf16, transposed)
  hipLaunchKernelGGL(k_wt, dim3(64,12), dim3(256), 0, stream,
                     f(2),f(4),f(6),f(8), f(10),f(12),f(14),f(16), f(18),f(20),f(22),f(24), wt);

  int SB = (n+255)/256;  // <=256 required for 2-level scan
  hipMemsetAsync(deg, 0, (size_t)n*4, stream);
  hipMemsetAsync(cur, 0, (size_t)n*4, stream);
  hipLaunchKernelGGL(k_count, dim3((E+255)/256), dim3(256), 0, stream, edst, deg, E);
  hipLaunchKernelGGL(k_scan1, dim3(SB), dim3(256), 0, stream, deg, offs, part, n);
  hipLaunchKernelGGL(k_scan2, dim3(1), dim3(256), 0, stream, part, SB);
  hipLaunchKernelGGL(k_scan3, dim3(SB), dim3(256), 0, stream, offs, part, n);
  hipLaunchKernelGGL(k_scatter, dim3((E+255)/256), dim3(256), 0, stream, esrc, edst, offs, cur, srcs, E);

  int RT = (n+63)/64;
  int AB = (n+3)/4;

  // layer 0
  hipLaunchKernelGGL(k_gemm, dim3(RT), dim3(256), 0, stream,
                     (const void*)x, 0, n, wt + 0*4*16384, f(3),f(5),f(7),f(9), 128, qkvs);
  hipLaunchKernelGGL(k_attn, dim3(AB), dim3(256), 0, stream, qkvs, offs, srcs, (void*)h1, 0, n);
  // layer 1
  hipLaunchKernelGGL(k_gemm, dim3(RT), dim3(256), 0, stream,
                     (const void*)h1, 1, n, wt + 1*4*16384, f(11),f(13),f(15),f(17), 128, qkvs);
  hipLaunchKernelGGL(k_attn, dim3(AB), dim3(256), 0, stream, qkvs, offs, srcs, (void*)h2, 0, n);
  // layer 2 (skip width 32, mean over heads)
  hipLaunchKernelGGL(k_gemm, dim3(RT), dim3(256), 0, stream,
                     (const void*)h2, 1, n, wt + 2*4*16384, f(19),f(21),f(23),f(25), 32, qkvs);
  hipLaunchKernelGGL(k_attn, dim3(AB), dim3(256), 0, stream, qkvs, offs, srcs, d_out, 1, n);
}

// Round 21
// 403.496 us; speedup vs baseline: 2.4424x; 2.4424x over previous
//
#include <hip/hip_runtime.h>
#include <cstdint>
#include <cstddef>

#define DIN 128       // feature width of all layer inputs (and Q/K/V width = H*DH)
#define ROW_BYTES 1024 // per-node row: Q bf16 [0,256) (head h at h*64)
                       //   K bf16 chunk-transposed [256,512): chunk j at 256+j*64 = [h0|h1|h2|h3]x16B
                       //   V bf16 chunk-transposed [512,768)
                       //   S bf16 linear [768,1024)

typedef __attribute__((ext_vector_type(8))) short short8v;
typedef __attribute__((ext_vector_type(4))) float float4v;

// ---------------- CSR build ----------------
__global__ void k_count(const int* __restrict__ dst, int* __restrict__ deg, int E){
  int i = blockIdx.x*blockDim.x + threadIdx.x;
  if(i<E) atomicAdd(&deg[dst[i]], 1);
}

__global__ void k_scan1(const int* __restrict__ deg, int* __restrict__ offs,
                        int* __restrict__ part, int n){
  __shared__ int sm[256];
  int t = threadIdx.x; int g = blockIdx.x*256 + t;
  int v = (g<n)? deg[g] : 0;
  sm[t] = v;
  for(int o=1;o<256;o<<=1){
    __syncthreads();
    int x = (t>=o)? sm[t-o] : 0;
    __syncthreads();
    sm[t] += x;
  }
  __syncthreads();
  if(g<n) offs[g+1] = sm[t];
  if(t==255) part[blockIdx.x] = sm[255];
}

__global__ void k_scan2(int* __restrict__ part, int nb){
  __shared__ int sm[256];
  int t=threadIdx.x;
  int v = (t<nb)? part[t] : 0;
  sm[t]=v;
  for(int o=1;o<256;o<<=1){ __syncthreads(); int x=(t>=o)?sm[t-o]:0; __syncthreads(); sm[t]+=x; }
  __syncthreads();
  if(t<nb) part[t] = sm[t]-v;  // exclusive prefix of block totals
}

__global__ void k_scan3(int* __restrict__ offs, const int* __restrict__ part, int n){
  int t=threadIdx.x; int g=blockIdx.x*256+t;
  if(g<n) offs[g+1] += part[blockIdx.x];
  if(g==0) offs[0]=0;
}

__global__ void k_scatter(const int* __restrict__ src, const int* __restrict__ dst,
                          const int* __restrict__ offs, int* __restrict__ cur,
                          int* __restrict__ srcs, int E){
  int i=blockIdx.x*blockDim.x+threadIdx.x;
  if(i<E){
    int d = dst[i];
    int p = atomicAdd(&cur[d],1);
    srcs[offs[d]+p] = src[i];
  }
}

// bf16 helpers (bf16 = top 16 bits of fp32; RNE pack)
__device__ inline unsigned f2bf(float x){
  unsigned u = __float_as_uint(x);
  return (u + 0x7FFFu + ((u>>16)&1u)) >> 16;
}
__device__ inline unsigned pack2(float a, float b){ return f2bf(a) | (f2bf(b)<<16); }
__device__ inline float bflo(unsigned w){ return __uint_as_float(w<<16); }
__device__ inline float bfhi(unsigned w){ return __uint_as_float(w & 0xFFFF0000u); }

// ---------------- weight prep: fp32 [din][dout] -> bf16 transposed [dout][din] ----------------
__global__ void k_wt(
  const float* __restrict__ W0, const float* __restrict__ W1, const float* __restrict__ W2,
  const float* __restrict__ W3, const float* __restrict__ W4, const float* __restrict__ W5,
  const float* __restrict__ W6, const float* __restrict__ W7, const float* __restrict__ W8,
  const float* __restrict__ W9, const float* __restrict__ W10, const float* __restrict__ W11,
  unsigned short* __restrict__ wt)
{
  int i = blockIdx.y;
  int e = blockIdx.x*256 + threadIdx.x;
  int dout = (i==11)? 32 : 128;
  if(e >= dout*128) return;
  const float* W;
  switch(i){
    case 0: W=W0; break; case 1: W=W1; break; case 2: W=W2; break; case 3: W=W3; break;
    case 4: W=W4; break; case 5: W=W5; break; case 6: W=W6; break; case 7: W=W7; break;
    case 8: W=W8; break; case 9: W=W9; break; case 10: W=W10; break; default: W=W11; break;
  }
  int c = e % dout, k = e / dout;
  wt[i*16384 + c*128 + k] = (unsigned short)f2bf(W[(size_t)k*dout + c]);
}

// ---------------- fused QKVS GEMM (bf16 MFMA, fp32 accum, 4 mats per block) ----------------
// grid: 1D row tiles. Block stages X ONCE. Passes linearized: p -> (mat=p>>1,
// half=p&1); next pass's 16KB W slice register-prefetched during this pass's
// MFMA (straight-line, static regs). Epilogue: Q,S bf16; K,V chunk-transposed.
__global__ __launch_bounds__(256,4) void k_gemm(
  const void* __restrict__ Xv, int xbf, int nrows,
  const unsigned short* __restrict__ Wt,
  const float* __restrict__ bq, const float* __restrict__ bk,
  const float* __restrict__ bv, const float* __restrict__ bs,
  int ws_cols, char* __restrict__ out)
{
  __shared__ unsigned short Xs[64][136];
  __shared__ unsigned short Wsh[64][136];
  int t = threadIdx.x;
  int row0 = blockIdx.x*64;
  int c = t>>2, kb = (t&3)*32;
  // ---- stage X (once) ----
  {
    int gr = row0 + c;
    if(gr < nrows){
      if(xbf){
        const unsigned short* xp = (const unsigned short*)Xv + (size_t)gr*DIN + kb;
        #pragma unroll
        for(int j=0;j<4;j++)
          *(uint4*)&Xs[c][kb + j*8] = *(const uint4*)(xp + j*8);
      } else {
        const float* xp = (const float*)Xv + (size_t)gr*DIN + kb;
        #pragma unroll
        for(int j=0;j<4;j++){
          float4 fa = *(const float4*)(xp + j*8);
          float4 fb = *(const float4*)(xp + j*8 + 4);
          uint4 pk = make_uint4(pack2(fa.x,fa.y), pack2(fa.z,fa.w),
                                pack2(fb.x,fb.y), pack2(fb.z,fb.w));
          *(uint4*)&Xs[c][kb + j*8] = pk;
        }
      }
    } else {
      uint4 z = make_uint4(0,0,0,0);
      #pragma unroll
      for(int j=0;j<4;j++) *(uint4*)&Xs[c][kb + j*8] = z;
    }
  }
  int wv = t>>6, l = t&63;
  int lr = l & 15, lk = (l>>4)*8;
  int P = (ws_cols > 64) ? 8 : 7;
  // prefetch pass 0 W slice (mat 0, half 0)
  uint4 w0, w1, w2, w3;
  {
    const unsigned short* wp = Wt + (size_t)c*128 + kb;
    w0 = *(const uint4*)(wp);
    w1 = *(const uint4*)(wp + 8);
    w2 = *(const uint4*)(wp + 16);
    w3 = *(const uint4*)(wp + 24);
  }
  for(int p=0; p<P; p++){
    int mat = p>>1, half = p&1;
    int wcols = (mat==3)? ws_cols : 128;
    int col0 = half*64;
    __syncthreads();    // prev pass's Wsh consumers done (p=0: Xs staged)
    *(uint4*)&Wsh[c][kb]      = w0;
    *(uint4*)&Wsh[c][kb + 8]  = w1;
    *(uint4*)&Wsh[c][kb + 16] = w2;
    *(uint4*)&Wsh[c][kb + 24] = w3;
    if(p+1 < P){
      int m2 = (p+1)>>1, h2 = (p+1)&1;
      const unsigned short* wp = Wt + m2*16384 + (size_t)(h2*64 + c)*128 + kb;
      w0 = *(const uint4*)(wp);
      w1 = *(const uint4*)(wp + 8);
      w2 = *(const uint4*)(wp + 16);
      w3 = *(const uint4*)(wp + 24);
    }
    __syncthreads();    // Wsh ready
    float4v acc[4];
    #pragma unroll
    for(int mt=0;mt<4;mt++) acc[mt] = (float4v){0.f,0.f,0.f,0.f};
    #pragma unroll
    for(int kk=0;kk<4;kk++){
      short8v b = *(const short8v*)&Wsh[wv*16 + lr][kk*32 + lk];
      #pragma unroll
      for(int mt=0;mt<4;mt++){
        short8v a = *(const short8v*)&Xs[mt*16 + lr][kk*32 + lk];
        acc[mt] = __builtin_amdgcn_mfma_f32_16x16x32_bf16(a, b, acc[mt], 0, 0, 0);
      }
    }
    const float* bias = (mat==0)?bq:(mat==1)?bk:(mat==2)?bv:bs;
    int col = col0 + wv*16 + lr;
    bool cok = col < wcols;
    float bcol = cok ? bias[col] : 0.f;
    int rb = row0 + (l>>4)*4;
    #pragma unroll
    for(int mt=0;mt<4;mt++){
      #pragma unroll
      for(int j=0;j<4;j++){
        int r = rb + mt*16 + j;
        if(r < nrows && cok){
          float val = acc[mt][j] + bcol;
          char* rowp = out + ((size_t)r<<10);
          if(mat==0)      *(unsigned short*)(rowp + col*2) = (unsigned short)f2bf(val);
          else if(mat==3) *(unsigned short*)(rowp + 768 + col*2) = (unsigned short)f2bf(val);
          else {
            int h = col>>5, d = col&31;
            int off = ((mat==1)?256:512) + (d>>3)*64 + h*16 + (d&7)*2;
            *(unsigned short*)(rowp + off) = (unsigned short)f2bf(val);
          }
        }
      }
    }
  }
}

// ---------------- per-node attention (online softmax, CSR, chunk-transposed bf16 KV) ----------------
// ROUND-13 configuration restored exactly — the measured optimum of this design:
// 256-thread blocks, 4 waves, one wave per node, __launch_bounds__(256,4),
// peeled first batch + online softmax, V loads pinned early, reduce-scatter
// epilogue. Closed experiments: more regs/wave -> spill (r11/r14/r16);
// L2 prefetch -> null (r19); 8 waves/SIMD -> 32-VGPR spill disaster (r20).
// mode 0: out bf16-packed [N][64] uints = relu(concat agg + skip)
// mode 1: out fp32 [N][32] = mean_h(agg) + skip
__global__ __launch_bounds__(256,4) void k_attn(
  const char* __restrict__ QKVS, const int* __restrict__ offs,
  const int* __restrict__ srcs, void* __restrict__ outv, int mode, int n)
{
  int wv = threadIdx.x>>6, lane = threadIdx.x&63;
  int node = blockIdx.x*4 + wv;
  if(node >= n) return;
  int h = lane & 3;
  int e_l = lane >> 2;
  const float rs = 0.17677669529663687f;  // 1/sqrt(32)
  const char* rowq = QKVS + ((size_t)node<<10) + h*64;
  uint4 qw[4];
  #pragma unroll
  for(int j=0;j<4;j++) qw[j] = *(const uint4*)(rowq + j*16);
  int beg = offs[node], end = offs[node+1];
  float m = 0.f, s = 0.f;
  float4 acc[8];
  #pragma unroll
  for(int j=0;j<8;j++) acc[j] = make_float4(0.f,0.f,0.f,0.f);

  if(beg < end){
    // ---- first batch (peeled: no rescale, acc = p*V) ----
    {
      int idx = beg + e_l;
      bool msk = idx < end;
      int sj = srcs[msk ? idx : beg];
      const char* base = QKVS + ((size_t)sj<<10) + 256 + h*16;
      uint4 vw[4];
      #pragma unroll
      for(int j=0;j<4;j++) vw[j] = *(const uint4*)(base + 256 + j*64);
      #pragma unroll
      for(int j=0;j<4;j++)
        asm volatile("" : "+v"(vw[j].x), "+v"(vw[j].y), "+v"(vw[j].z), "+v"(vw[j].w));
      float dot = 0.f;
      #pragma unroll
      for(int j=0;j<4;j++){
        uint4 kwj = *(const uint4*)(base + j*64);
        uint4 qj = qw[j];
        dot += bflo(qj.x)*bflo(kwj.x) + bfhi(qj.x)*bfhi(kwj.x)
             + bflo(qj.y)*bflo(kwj.y) + bfhi(qj.y)*bfhi(kwj.y)
             + bflo(qj.z)*bflo(kwj.z) + bfhi(qj.z)*bfhi(kwj.z)
             + bflo(qj.w)*bflo(kwj.w) + bfhi(qj.w)*bfhi(kwj.w);
      }
      dot *= rs;
      float logit = msk ? dot : -__builtin_inff();
      float bm = logit;
      bm = fmaxf(bm, __shfl_xor(bm,4));
      bm = fmaxf(bm, __shfl_xor(bm,8));
      bm = fmaxf(bm, __shfl_xor(bm,16));
      bm = fmaxf(bm, __shfl_xor(bm,32));
      float p = __expf(logit - bm);   // invalid lanes -> 0
      float ps = p;
      ps += __shfl_xor(ps,4); ps += __shfl_xor(ps,8); ps += __shfl_xor(ps,16); ps += __shfl_xor(ps,32);
      s = ps; m = bm;
      #pragma unroll
      for(int j=0;j<4;j++){
        uint4 w = vw[j];
        acc[2*j]   = make_float4(p*bflo(w.x), p*bfhi(w.x), p*bflo(w.y), p*bfhi(w.y));
        acc[2*j+1] = make_float4(p*bflo(w.z), p*bfhi(w.z), p*bflo(w.w), p*bfhi(w.w));
      }
    }
    // ---- remaining batches (online softmax with rescale) ----
    for(int b0 = beg+16; b0 < end; b0 += 16){
      int idx = b0 + e_l;
      bool msk = idx < end;
      int sj = srcs[msk ? idx : beg];
      const char* base = QKVS + ((size_t)sj<<10) + 256 + h*16;
      uint4 vw[4];
      #pragma unroll
      for(int j=0;j<4;j++) vw[j] = *(const uint4*)(base + 256 + j*64);
      #pragma unroll
      for(int j=0;j<4;j++)
        asm volatile("" : "+v"(vw[j].x), "+v"(vw[j].y), "+v"(vw[j].z), "+v"(vw[j].w));
      float dot = 0.f;
      #pragma unroll
      for(int j=0;j<4;j++){
        uint4 kwj = *(const uint4*)(base + j*64);
        uint4 qj = qw[j];
        dot += bflo(qj.x)*bflo(kwj.x) + bfhi(qj.x)*bfhi(kwj.x)
             + bflo(qj.y)*bflo(kwj.y) + bfhi(qj.y)*bfhi(kwj.y)
             + bflo(qj.z)*bflo(kwj.z) + bfhi(qj.z)*bfhi(kwj.z)
             + bflo(qj.w)*bflo(kwj.w) + bfhi(qj.w)*bfhi(kwj.w);
      }
      dot *= rs;
      float logit = msk ? dot : -__builtin_inff();
      float bm = logit;
      bm = fmaxf(bm, __shfl_xor(bm,4));
      bm = fmaxf(bm, __shfl_xor(bm,8));
      bm = fmaxf(bm, __shfl_xor(bm,16));
      bm = fmaxf(bm, __shfl_xor(bm,32));
      float mn = fmaxf(m, bm);
      float r = __expf(m - mn);
      float p = __expf(logit - mn);   // invalid lanes -> 0
      float ps = p;
      ps += __shfl_xor(ps,4); ps += __shfl_xor(ps,8); ps += __shfl_xor(ps,16); ps += __shfl_xor(ps,32);
      s = r*s + ps; m = mn;
      #pragma unroll
      for(int j=0;j<4;j++){
        uint4 w = vw[j];
        float4 a0 = acc[2*j], a1 = acc[2*j+1];
        a0.x = fmaf(a0.x, r, p*bflo(w.x)); a0.y = fmaf(a0.y, r, p*bfhi(w.x));
        a0.z = fmaf(a0.z, r, p*bflo(w.y)); a0.w = fmaf(a0.w, r, p*bfhi(w.y));
        a1.x = fmaf(a1.x, r, p*bflo(w.z)); a1.y = fmaf(a1.y, r, p*bfhi(w.z));
        a1.z = fmaf(a1.z, r, p*bflo(w.w)); a1.w = fmaf(a1.w, r, p*bfhi(w.w));
        acc[2*j] = a0; acc[2*j+1] = a1;
      }
    }
  }
  // ---- reduce-scatter over edge lanes: 30 shfl total ----
  int b5 = (lane>>5)&1, b4 = (lane>>4)&1, b3 = (lane>>3)&1, b2 = (lane>>2)&1;
  float4 r4[4];
  #pragma unroll
  for(int j=0;j<4;j++){
    float4 keep = b5 ? acc[j+4] : acc[j];
    float4 send = b5 ? acc[j]   : acc[j+4];
    keep.x += __shfl_xor(send.x,32); keep.y += __shfl_xor(send.y,32);
    keep.z += __shfl_xor(send.z,32); keep.w += __shfl_xor(send.w,32);
    r4[j] = keep;   // ch = 16*b5 + 4*j + c
  }
  float4 r2[2];
  #pragma unroll
  for(int j=0;j<2;j++){
    float4 keep = b4 ? r4[j+2] : r4[j];
    float4 send = b4 ? r4[j]   : r4[j+2];
    keep.x += __shfl_xor(send.x,16); keep.y += __shfl_xor(send.y,16);
    keep.z += __shfl_xor(send.z,16); keep.w += __shfl_xor(send.w,16);
    r2[j] = keep;   // ch = 16*b5 + 8*b4 + 4*j + c
  }
  float4 r1;
  {
    float4 keep = b3 ? r2[1] : r2[0];
    float4 send = b3 ? r2[0] : r2[1];
    keep.x += __shfl_xor(send.x,8); keep.y += __shfl_xor(send.y,8);
    keep.z += __shfl_xor(send.z,8); keep.w += __shfl_xor(send.w,8);
    r1 = keep;      // ch = 16*b5 + 8*b4 + 4*b3 + c
  }
  float fx, fy;
  {
    float kx = b2 ? r1.z : r1.x, ky = b2 ? r1.w : r1.y;
    float sx = b2 ? r1.x : r1.z, sy = b2 ? r1.y : r1.w;
    fx = kx + __shfl_xor(sx,4);
    fy = ky + __shfl_xor(sy,4);   // ch pair = (2*e_l, 2*e_l+1) of head h
  }
  float inv = (s > 0.f) ? (1.f/s) : 0.f;
  if(mode == 0){
    unsigned sw = *(const unsigned*)(QKVS + ((size_t)node<<10) + 768 + h*64 + e_l*4);
    float ox = fmaxf(fmaf(fx, inv, bflo(sw)), 0.f);
    float oy = fmaxf(fmaf(fy, inv, bfhi(sw)), 0.f);
    ((unsigned*)outv)[(size_t)node*64 + h*16 + e_l] = pack2(ox, oy);
  } else {
    float sc = inv*0.25f;
    float ox = fx*sc, oy = fy*sc;
    ox += __shfl_xor(ox,1); oy += __shfl_xor(oy,1);
    ox += __shfl_xor(ox,2); oy += __shfl_xor(oy,2);
    if(h == 0){
      unsigned sw = *(const unsigned*)(QKVS + ((size_t)node<<10) + 768 + e_l*4);
      float* op = (float*)outv + (size_t)node*32 + 2*e_l;
      op[0] = ox + bflo(sw); op[1] = oy + bfhi(sw);
    }
  }
}

extern "C" void kernel_launch(void* const* d_in, const int* in_sizes, int n_in,
                              void* d_out, int out_size, void* d_ws, size_t ws_size,
                              hipStream_t stream) {
  const float* x = (const float*)d_in[0];
  const int* ei = (const int*)d_in[1];
  int n = in_sizes[0]/DIN;
  int E = in_sizes[1]/2;
  const int* esrc = ei;
  const int* edst = ei + E;

  char* w = (char*)d_ws;
  auto alloc = [&](size_t bytes)->char*{
    char* p = w; w += (bytes + 255) & ~(size_t)255; return p;
  };
  int* offs = (int*)alloc((size_t)(n+1)*4);
  int* deg  = (int*)alloc((size_t)n*4);
  int* cur  = (int*)alloc((size_t)n*4);
  int* part = (int*)alloc(256*4);
  int* srcs = (int*)alloc((size_t)E*4);
  char* qkvs = alloc((size_t)n*ROW_BYTES);
  unsigned short* h1 = (unsigned short*)alloc((size_t)n*128*2);
  unsigned short* h2 = (unsigned short*)alloc((size_t)n*128*2);
  unsigned short* wt = (unsigned short*)alloc((size_t)12*16384*2);

  auto f = [&](int i)->const float*{ return (const float*)d_in[i]; };

  // weight prep (bf16, transposed)
  hipLaunchKernelGGL(k_wt, dim3(64,12), dim3(256), 0, stream,
                     f(2),f(4),f(6),f(8), f(10),f(12),f(14),f(16), f(18),f(20),f(22),f(24), wt);

  int SB = (n+255)/256;  // <=256 required for 2-level scan
  hipMemsetAsync(deg, 0, (size_t)n*4, stream);
  hipMemsetAsync(cur, 0, (size_t)n*4, stream);
  hipLaunchKernelGGL(k_count, dim3((E+255)/256), dim3(256), 0, stream, edst, deg, E);
  hipLaunchKernelGGL(k_scan1, dim3(SB), dim3(256), 0, stream, deg, offs, part, n);
  hipLaunchKernelGGL(k_scan2, dim3(1), dim3(256), 0, stream, part, SB);
  hipLaunchKernelGGL(k_scan3, dim3(SB), dim3(256), 0, stream, offs, part, n);
  hipLaunchKernelGGL(k_scatter, dim3((E+255)/256), dim3(256), 0, stream, esrc, edst, offs, cur, srcs, E);

  int RT = (n+63)/64;
  int AB = (n+3)/4;

  // layer 0
  hipLaunchKernelGGL(k_gemm, dim3(RT), dim3(256), 0, stream,
                     (const void*)x, 0, n, wt + 0*4*16384, f(3),f(5),f(7),f(9), 128, qkvs);
  hipLaunchKernelGGL(k_attn, dim3(AB), dim3(256), 0, stream, qkvs, offs, srcs, (void*)h1, 0, n);
  // layer 1
  hipLaunchKernelGGL(k_gemm, dim3(RT), dim3(256), 0, stream,
                     (const void*)h1, 1, n, wt + 1*4*16384, f(11),f(13),f(15),f(17), 128, qkvs);
  hipLaunchKernelGGL(k_attn, dim3(AB), dim3(256), 0, stream, qkvs, offs, srcs, (void*)h2, 0, n);
  // layer 2 (skip width 32, mean over heads)
  hipLaunchKernelGGL(k_gemm, dim3(RT), dim3(256), 0, stream,
                     (const void*)h2, 1, n, wt + 2*4*16384, f(19),f(21),f(23),f(25), 32, qkvs);
  hipLaunchKernelGGL(k_attn, dim3(AB), dim3(256), 0, stream, qkvs, offs, srcs, d_out, 1, n);
}